// Round 1
// baseline (1120.893 us; speedup 1.0000x reference)
//
#include <hip/hip_runtime.h>
#include <math.h>

#define DIM 128
#define NGRAPH 4096

// Order-preserving float atomic max: non-negative values compare correctly as
// signed ints; negative values compare reverse as unsigned ints. Init = -inf
// (0xFF800000) is the unsigned-max among negatives, so either path wins over it.
__device__ __forceinline__ void atomicMaxF(float* addr, float val) {
    if (!(val > -INFINITY)) return;  // skip -inf and NaN (no-op vs -inf init)
    if (val >= 0.f)
        atomicMax((int*)addr, __float_as_int(val));
    else
        atomicMin((unsigned int*)addr, (unsigned int)__float_as_int(val));
}

__global__ void init_kernel(float* __restrict__ out, int out_n,
                            float* __restrict__ gmax, float* __restrict__ gsum, int ngraph) {
    int i = blockIdx.x * blockDim.x + threadIdx.x;
    if (i < out_n) out[i] = 0.f;
    if (i < ngraph) { gmax[i] = -INFINITY; gsum[i] = 0.f; }
}

__global__ void segmax_kernel(const float* __restrict__ lp, const int* __restrict__ batch,
                              float* __restrict__ gmax, int n) {
    int base = (blockIdx.x * blockDim.x + threadIdx.x) * 4;
    if (base >= n) return;
    float cur = -INFINITY;
    int cg = batch[base];
    #pragma unroll
    for (int k = 0; k < 4; k++) {
        int i = base + k;
        if (i >= n) break;
        float l = lp[i];
        int b = batch[i];
        float nl = (fabsf(l) < INFINITY) ? -l : -INFINITY;  // NaN -> -inf (invalid)
        if (b != cg) { atomicMaxF(&gmax[cg], cur); cg = b; cur = nl; }
        else cur = fmaxf(cur, nl);
    }
    atomicMaxF(&gmax[cg], cur);
}

__global__ void segsum_kernel(const float* __restrict__ lp, const int* __restrict__ batch,
                              const float* __restrict__ gmax, float* __restrict__ gsum, int n) {
    int base = (blockIdx.x * blockDim.x + threadIdx.x) * 4;
    if (base >= n) return;
    float cur = 0.f;
    int cg = batch[base];
    #pragma unroll
    for (int k = 0; k < 4; k++) {
        int i = base + k;
        if (i >= n) break;
        float l = lp[i];
        int b = batch[i];
        float m = gmax[b];
        if (!(fabsf(m) < INFINITY)) m = 0.f;   // empty-graph guard (matches reference)
        float e = (fabsf(l) < INFINITY) ? __expf(-l - m) : 0.f;
        if (b != cg) { atomicAdd(&gsum[cg], cur); cg = b; cur = e; }
        else cur += e;
    }
    atomicAdd(&gsum[cg], cur);
}

// One wave (64 lanes) owns a contiguous chunk of rows; lane owns columns
// (2*lane, 2*lane+1). Register accumulation; atomic flush only at graph
// boundaries and chunk ends (batch is sorted -> boundaries are rare).
__launch_bounds__(256)
__global__ void agg_kernel(const float* __restrict__ emb, const int* __restrict__ batch,
                           const float* __restrict__ lp, const float* __restrict__ gmax,
                           const float* __restrict__ gsum, float* __restrict__ out,
                           int rows_per_wave, int n) {
    int wave = (int)((blockIdx.x * blockDim.x + threadIdx.x) >> 6);
    int lane = (int)(threadIdx.x & 63);
    long r0 = (long)wave * rows_per_wave;
    if (r0 >= n) return;
    long r1 = r0 + rows_per_wave;
    if (r1 > n) r1 = n;

    const float2* __restrict__ emb2 = (const float2*)emb;  // row i -> emb2[i*64 + lane]
    float2 acc = make_float2(0.f, 0.f);
    int cg = batch[r0];

    for (long i = r0; i < r1; i += 8) {
        float2 v[8];
        int b[8];
        float w[8];
        #pragma unroll
        for (int k = 0; k < 8; k++) {
            long r = i + k;
            if (r < r1) {
                v[k] = emb2[((size_t)r << 6) + lane];
                b[k] = batch[r];
                float l = lp[r];
                float m = gmax[b[k]];
                if (!(fabsf(m) < INFINITY)) m = 0.f;
                float e = (fabsf(l) < INFINITY) ? __expf(-l - m) : 0.f;
                w[k] = e / fmaxf(gsum[b[k]], 1e-8f);
            } else {
                v[k] = make_float2(0.f, 0.f);
                b[k] = cg;
                w[k] = 0.f;
            }
        }
        #pragma unroll
        for (int k = 0; k < 8; k++) {
            if (b[k] != cg) {   // wave-uniform branch (all lanes share b[k])
                size_t o = ((size_t)cg << 7) + ((size_t)lane << 1);
                atomicAdd(out + o, acc.x);
                atomicAdd(out + o + 1, acc.y);
                acc.x = 0.f; acc.y = 0.f;
                cg = b[k];
            }
            acc.x += v[k].x * w[k];
            acc.y += v[k].y * w[k];
        }
    }
    size_t o = ((size_t)cg << 7) + ((size_t)lane << 1);
    atomicAdd(out + o, acc.x);
    atomicAdd(out + o + 1, acc.y);
}

extern "C" void kernel_launch(void* const* d_in, const int* in_sizes, int n_in,
                              void* d_out, int out_size, void* d_ws, size_t ws_size,
                              hipStream_t stream) {
    const float* emb   = (const float*)d_in[0];
    const int*   batch = (const int*)d_in[1];
    const float* lp    = (const float*)d_in[2];
    float* out  = (float*)d_out;
    float* gmax = (float*)d_ws;
    float* gsum = gmax + NGRAPH;

    int n = in_sizes[1];          // number of subgraphs (1048576)
    int out_n = out_size;         // 4096 * 128

    // 1) init output + workspace (harness poisons both with 0xAA)
    {
        int tot = out_n > NGRAPH ? out_n : NGRAPH;
        int blocks = (tot + 255) / 256;
        init_kernel<<<blocks, 256, 0, stream>>>(out, out_n, gmax, gsum, NGRAPH);
    }
    // 2) segment max of -log_p
    {
        int threads_needed = (n + 3) / 4;
        int blocks = (threads_needed + 255) / 256;
        segmax_kernel<<<blocks, 256, 0, stream>>>(lp, batch, gmax, n);
    }
    // 3) segment sum of exp(-log_p - max)
    {
        int threads_needed = (n + 3) / 4;
        int blocks = (threads_needed + 255) / 256;
        segsum_kernel<<<blocks, 256, 0, stream>>>(lp, batch, gmax, gsum, n);
    }
    // 4) weighted aggregation (the 512 MB pass)
    {
        const int rows_per_wave = 512;
        int total_waves = (n + rows_per_wave - 1) / rows_per_wave;   // 2048
        int blocks = (total_waves + 3) / 4;                          // 4 waves/block
        agg_kernel<<<blocks, 256, 0, stream>>>(emb, batch, lp, gmax, gsum, out,
                                               rows_per_wave, n);
    }
}